// Round 1
// baseline (2705.462 us; speedup 1.0000x reference)
//
#include <hip/hip_runtime.h>
#include <math.h>

#define N_NODES 50000
#define N_EDGES 800000
#define DIM 96

__global__ void count_deg(const int* __restrict__ dst, int* __restrict__ deg) {
    int i = blockIdx.x * blockDim.x + threadIdx.x;
    if (i < N_EDGES) atomicAdd(&deg[dst[i]], 1);
}

__global__ void compute_norm(const int* __restrict__ deg, float* __restrict__ norm) {
    int i = blockIdx.x * blockDim.x + threadIdx.x;
    if (i < N_NODES) {
        float d = (float)deg[i];
        norm[i] = 1.0f / sqrtf(fmaxf(d, 1.0f));
    }
}

// out[n][j] = (dot(X[n,:], W[j,:]) + b[j]) * norm[n]
__global__ void gemm_bias_norm(const float* __restrict__ X, const float* __restrict__ W,
                               const float* __restrict__ b, const float* __restrict__ norm,
                               float* __restrict__ out) {
    int idx = blockIdx.x * blockDim.x + threadIdx.x;
    if (idx >= N_NODES * DIM) return;
    int n = idx / DIM;
    int j = idx - n * DIM;
    const float4* xr = (const float4*)(X + (size_t)n * DIM);
    const float4* wr = (const float4*)(W + (size_t)j * DIM);
    float acc = 0.f;
#pragma unroll
    for (int k = 0; k < DIM / 4; ++k) {
        float4 a = xr[k];
        float4 w = wr[k];
        acc += a.x * w.x + a.y * w.y + a.z * w.z + a.w * w.w;
    }
    out[idx] = (acc + b[j]) * norm[n];
}

// one thread per (edge, float4 chunk): 24 chunks per edge
__global__ void scatter_edges(const float* __restrict__ feat, const float* __restrict__ factor,
                              const int* __restrict__ src, const int* __restrict__ dst,
                              float* __restrict__ agg) {
    int idx = blockIdx.x * blockDim.x + threadIdx.x;
    if (idx >= N_EDGES * (DIM / 4)) return;
    int e = idx / (DIM / 4);
    int c = idx - e * (DIM / 4);
    int s = src[e];
    int d = dst[e];
    float f = factor[e];
    float4 v = ((const float4*)(feat + (size_t)s * DIM))[c];
    float* o = agg + (size_t)d * DIM + (size_t)c * 4;
    atomicAdd(o + 0, v.x * f);
    atomicAdd(o + 1, v.y * f);
    atomicAdd(o + 2, v.z * f);
    atomicAdd(o + 3, v.w * f);
}

__global__ void tanh_inplace(float* __restrict__ x, int n) {
    int i = blockIdx.x * blockDim.x + threadIdx.x;
    if (i < n) x[i] = tanhf(x[i]);
}

// fused tanh + column sum; total threads = 192*104 = 19968, a multiple of 96,
// so each thread's column (gtid % 96) is invariant under the grid stride.
__global__ void tanh_colsum(const float* __restrict__ agg, float* __restrict__ pooled) {
    int gtid = blockIdx.x * blockDim.x + threadIdx.x;
    const int T = 192 * 104;
    float s = 0.f;
    for (int i = gtid; i < N_NODES * DIM; i += T) s += tanhf(agg[i]);
    atomicAdd(&pooled[gtid % DIM], s);
}

__global__ void final_tanh(const float* __restrict__ pooled, float* __restrict__ out) {
    int j = threadIdx.x;
    if (j < DIM) out[j] = tanhf(pooled[j] * (1.0f / N_NODES));
}

extern "C" void kernel_launch(void* const* d_in, const int* in_sizes, int n_in,
                              void* d_out, int out_size, void* d_ws, size_t ws_size,
                              hipStream_t stream) {
    const float* inputs = (const float*)d_in[0];
    const float* W1     = (const float*)d_in[1];
    const float* b1     = (const float*)d_in[2];
    const float* W2     = (const float*)d_in[3];
    const float* b2     = (const float*)d_in[4];
    const float* factor = (const float*)d_in[5];
    const int*   src    = (const int*)d_in[6];
    const int*   dst    = (const int*)d_in[7];
    float* out = (float*)d_out;

    char* ws = (char*)d_ws;
    const size_t FEAT_BYTES = (size_t)N_NODES * DIM * sizeof(float); // 19.2 MB
    int*   deg    = (int*)ws;                                   // 200 KB
    float* norm   = (float*)(ws + 262144);                      // 200 KB
    float* bufA   = (float*)(ws + 524288);                      // feat buffer
    float* bufB   = (float*)(ws + 524288 + 20971520);           // agg/h buffer
    float* pooled = (float*)(ws + 524288 + 2ull * 20971520);    // 96 floats

    // degree + norm
    hipMemsetAsync(deg, 0, N_NODES * sizeof(int), stream);
    count_deg<<<(N_EDGES + 255) / 256, 256, 0, stream>>>(dst, deg);
    compute_norm<<<(N_NODES + 255) / 256, 256, 0, stream>>>(deg, norm);

    // layer 1
    gemm_bias_norm<<<(N_NODES * DIM + 255) / 256, 256, 0, stream>>>(inputs, W1, b1, norm, bufA);
    hipMemsetAsync(bufB, 0, FEAT_BYTES, stream);
    scatter_edges<<<(N_EDGES * (DIM / 4) + 255) / 256, 256, 0, stream>>>(bufA, factor, src, dst, bufB);
    tanh_inplace<<<(N_NODES * DIM + 255) / 256, 256, 0, stream>>>(bufB, N_NODES * DIM);

    // layer 2
    gemm_bias_norm<<<(N_NODES * DIM + 255) / 256, 256, 0, stream>>>(bufB, W2, b2, norm, bufA);
    hipMemsetAsync(bufB, 0, FEAT_BYTES, stream);
    scatter_edges<<<(N_EDGES * (DIM / 4) + 255) / 256, 256, 0, stream>>>(bufA, factor, src, dst, bufB);

    // pooled mean + tanh
    hipMemsetAsync(pooled, 0, DIM * sizeof(float), stream);
    tanh_colsum<<<104, 192, 0, stream>>>(bufB, pooled);
    final_tanh<<<1, 128, 0, stream>>>(pooled, out);
}

// Round 2
// 931.660 us; speedup vs baseline: 2.9039x; 2.9039x over previous
//
#include <hip/hip_runtime.h>
#include <math.h>

#define N_NODES 50000
#define N_EDGES 800000
#define DIM 96
#define CHUNKS (DIM / 4)   // 24 float4 chunks per node

__global__ void count_deg(const int* __restrict__ dst, int* __restrict__ deg) {
    int i = blockIdx.x * blockDim.x + threadIdx.x;
    if (i < N_EDGES) atomicAdd(&deg[dst[i]], 1);
}

// single-block exclusive scan: offs[0]=0, offs[i+1]=sum(deg[0..i]); also seeds cursor
__global__ void scan_deg(const int* __restrict__ deg, int* __restrict__ offs,
                         int* __restrict__ cursor) {
    __shared__ int sm[1024];
    __shared__ int carry;
    int tid = threadIdx.x;
    if (tid == 0) { carry = 0; offs[0] = 0; cursor[0] = 0; }
    __syncthreads();
    for (int base = 0; base < N_NODES; base += 1024) {
        int v = (base + tid < N_NODES) ? deg[base + tid] : 0;
        sm[tid] = v;
        __syncthreads();
        for (int off = 1; off < 1024; off <<= 1) {
            int t = (tid >= off) ? sm[tid - off] : 0;
            __syncthreads();
            sm[tid] += t;
            __syncthreads();
        }
        int incl = sm[tid] + carry;
        if (base + tid < N_NODES) {
            offs[base + tid + 1] = incl;
            cursor[base + tid] = incl - v;   // exclusive prefix = start cursor
        }
        __syncthreads();
        if (tid == 1023) carry = incl;
        __syncthreads();
    }
}

__global__ void compute_norm(const int* __restrict__ deg, float* __restrict__ norm) {
    int i = blockIdx.x * blockDim.x + threadIdx.x;
    if (i < N_NODES) {
        float d = (float)deg[i];
        norm[i] = 1.0f / sqrtf(fmaxf(d, 1.0f));
    }
}

__global__ void fill_csr(const int* __restrict__ src, const int* __restrict__ dst,
                         const float* __restrict__ factor,
                         int* __restrict__ cursor, int2* __restrict__ entries) {
    int e = blockIdx.x * blockDim.x + threadIdx.x;
    if (e >= N_EDGES) return;
    int pos = atomicAdd(&cursor[dst[e]], 1);
    entries[pos] = make_int2(src[e], __float_as_int(factor[e]));
}

// out[n][j] = (dot(X[n,:], W[j,:]) + b[j]) * norm[n]
__global__ void gemm_bias_norm(const float* __restrict__ X, const float* __restrict__ W,
                               const float* __restrict__ b, const float* __restrict__ norm,
                               float* __restrict__ out) {
    int idx = blockIdx.x * blockDim.x + threadIdx.x;
    if (idx >= N_NODES * DIM) return;
    int n = idx / DIM;
    int j = idx - n * DIM;
    const float4* xr = (const float4*)(X + (size_t)n * DIM);
    const float4* wr = (const float4*)(W + (size_t)j * DIM);
    float acc = 0.f;
#pragma unroll
    for (int k = 0; k < DIM / 4; ++k) {
        float4 a = xr[k];
        float4 w = wr[k];
        acc += a.x * w.x + a.y * w.y + a.z * w.z + a.w * w.w;
    }
    out[idx] = (acc + b[j]) * norm[n];
}

// gather aggregation: thread = (node, float4 chunk); register accumulate, one store
template <bool DO_TANH>
__global__ void gather_agg(const float* __restrict__ feat, const int* __restrict__ offs,
                           const int2* __restrict__ entries, float* __restrict__ out) {
    int idx = blockIdx.x * blockDim.x + threadIdx.x;
    if (idx >= N_NODES * CHUNKS) return;
    int n = idx / CHUNKS;
    int c = idx - n * CHUNKS;
    int beg = offs[n], end = offs[n + 1];
    float4 acc = make_float4(0.f, 0.f, 0.f, 0.f);
    for (int p = beg; p < end; ++p) {
        int2 en = entries[p];
        float f = __int_as_float(en.y);
        float4 v = ((const float4*)(feat + (size_t)en.x * DIM))[c];
        acc.x += v.x * f; acc.y += v.y * f; acc.z += v.z * f; acc.w += v.w * f;
    }
    if (DO_TANH) {
        acc.x = tanhf(acc.x); acc.y = tanhf(acc.y);
        acc.z = tanhf(acc.z); acc.w = tanhf(acc.w);
    }
    ((float4*)out)[idx] = acc;
}

// fused tanh + column sum; 192*104 threads = multiple of 96 so column is loop-invariant
__global__ void tanh_colsum(const float* __restrict__ agg, float* __restrict__ pooled) {
    int gtid = blockIdx.x * blockDim.x + threadIdx.x;
    const int T = 192 * 104;
    float s = 0.f;
    for (int i = gtid; i < N_NODES * DIM; i += T) s += tanhf(agg[i]);
    atomicAdd(&pooled[gtid % DIM], s);
}

__global__ void final_tanh(const float* __restrict__ pooled, float* __restrict__ out) {
    int j = threadIdx.x;
    if (j < DIM) out[j] = tanhf(pooled[j] * (1.0f / N_NODES));
}

extern "C" void kernel_launch(void* const* d_in, const int* in_sizes, int n_in,
                              void* d_out, int out_size, void* d_ws, size_t ws_size,
                              hipStream_t stream) {
    const float* inputs = (const float*)d_in[0];
    const float* W1     = (const float*)d_in[1];
    const float* b1     = (const float*)d_in[2];
    const float* W2     = (const float*)d_in[3];
    const float* b2     = (const float*)d_in[4];
    const float* factor = (const float*)d_in[5];
    const int*   src    = (const int*)d_in[6];
    const int*   dst    = (const int*)d_in[7];
    float* out = (float*)d_out;

    char* ws = (char*)d_ws;
    int*   deg     = (int*)(ws + 0);                 // 200 KB
    int*   offs    = (int*)(ws + 204800);            // 200 KB (+1)
    int*   cursor  = (int*)(ws + 409600);            // 200 KB
    float* norm    = (float*)(ws + 614400);          // 200 KB
    int2*  entries = (int2*)(ws + 819200);           // 6.4 MB
    float* bufA    = (float*)(ws + 7340032);         // 19.2 MB
    float* bufB    = (float*)(ws + 26542080);        // 19.2 MB
    float* pooled  = (float*)(ws + 45744128);        // 384 B

    // degree + CSR build + norm
    hipMemsetAsync(deg, 0, N_NODES * sizeof(int), stream);
    count_deg<<<(N_EDGES + 255) / 256, 256, 0, stream>>>(dst, deg);
    scan_deg<<<1, 1024, 0, stream>>>(deg, offs, cursor);
    compute_norm<<<(N_NODES + 255) / 256, 256, 0, stream>>>(deg, norm);
    fill_csr<<<(N_EDGES + 255) / 256, 256, 0, stream>>>(src, dst, factor, cursor, entries);

    const int AGG_THREADS = N_NODES * CHUNKS;

    // layer 1: feat = (X@W1^T + b1)*norm ; h = tanh(gather(feat))
    gemm_bias_norm<<<(N_NODES * DIM + 255) / 256, 256, 0, stream>>>(inputs, W1, b1, norm, bufA);
    gather_agg<true><<<(AGG_THREADS + 255) / 256, 256, 0, stream>>>(bufA, offs, entries, bufB);

    // layer 2: feat = (h@W2^T + b2)*norm ; agg = gather(feat)
    gemm_bias_norm<<<(N_NODES * DIM + 255) / 256, 256, 0, stream>>>(bufB, W2, b2, norm, bufA);
    gather_agg<false><<<(AGG_THREADS + 255) / 256, 256, 0, stream>>>(bufA, offs, entries, bufB);

    // pooled mean + tanh
    hipMemsetAsync(pooled, 0, DIM * sizeof(float), stream);
    tanh_colsum<<<104, 192, 0, stream>>>(bufB, pooled);
    final_tanh<<<1, 128, 0, stream>>>(pooled, out);
}

// Round 3
// 508.141 us; speedup vs baseline: 5.3242x; 1.8335x over previous
//
#include <hip/hip_runtime.h>
#include <math.h>

#define N_NODES 50000
#define N_EDGES 800000
#define DIM 96
#define CHUNKS (DIM / 4)   // 24 float4 chunks per node

// ---------------- degree / CSR build ----------------

__global__ void count_deg(const int* __restrict__ dst, int* __restrict__ deg) {
    int i = blockIdx.x * blockDim.x + threadIdx.x;
    if (i < N_EDGES) atomicAdd(&deg[dst[i]], 1);
}

// single-block scan: offs[i] = sum(deg[0..i-1]), offs[N]=total; cursor=exclusive;
// fused norm[i] = rsqrt(max(deg,1)).  Each thread owns 49 contiguous elements.
__global__ void scan_deg_norm(const int* __restrict__ deg, int* __restrict__ offs,
                              int* __restrict__ cursor, float* __restrict__ norm) {
    __shared__ int sums[1024];
    const int PER = 49;  // 1024*49 = 50176 >= 50000
    int tid = threadIdx.x;
    int base = tid * PER;
    int s = 0;
    for (int i = 0; i < PER; ++i) {
        int idx = base + i;
        if (idx < N_NODES) s += deg[idx];
    }
    sums[tid] = s;
    __syncthreads();
    for (int off = 1; off < 1024; off <<= 1) {
        int t = (tid >= off) ? sums[tid - off] : 0;
        __syncthreads();
        sums[tid] += t;
        __syncthreads();
    }
    int e = (tid > 0) ? sums[tid - 1] : 0;   // exclusive prefix of this chunk
    for (int i = 0; i < PER; ++i) {
        int idx = base + i;
        if (idx < N_NODES) {
            int v = deg[idx];
            offs[idx] = e;
            cursor[idx] = e;
            norm[idx] = rsqrtf(fmaxf((float)v, 1.0f));
            e += v;
        }
    }
    if (tid == 1023) offs[N_NODES] = sums[1023];
}

__global__ void fill_csr(const int* __restrict__ src, const int* __restrict__ dst,
                         const float* __restrict__ factor,
                         int* __restrict__ cursor, int2* __restrict__ entries) {
    int e = blockIdx.x * blockDim.x + threadIdx.x;
    if (e >= N_EDGES) return;
    int pos = atomicAdd(&cursor[dst[e]], 1);
    entries[pos] = make_int2(src[e], __float_as_int(factor[e]));
}

// ---------------- LDS-tiled GEMM:  out[n][j] = (dot(X[n,:],W[j,:]) + b[j]) * norm[n] ----------------

#define MT 64            // nodes per block
#define XS_STRIDE 100    // pad 96 -> 100 words: node-group stride 400 % 32 = 16 -> 2-way (free)
#define WS_STRIDE 100

__global__ void gemm_tiled(const float* __restrict__ X, const float* __restrict__ W,
                           const float* __restrict__ b, const float* __restrict__ norm,
                           float* __restrict__ out) {
    __shared__ float Xs[MT * XS_STRIDE];    // 25.6 KB
    __shared__ float Ws[DIM * WS_STRIDE];   // 38.4 KB
    int tid = threadIdx.x;
    int nbase = blockIdx.x * MT;

    // stage X tile: 64 rows x 24 float4 = 1536 float4 (6 per thread)
#pragma unroll
    for (int it = 0; it < 6; ++it) {
        int idx = tid + 256 * it;
        int row = idx / 24, c = idx % 24;
        int n = nbase + row;
        float4 v = make_float4(0.f, 0.f, 0.f, 0.f);
        if (n < N_NODES) v = ((const float4*)(X + (size_t)n * DIM))[c];
        *((float4*)&Xs[row * XS_STRIDE + c * 4]) = v;
    }
    // stage all of W: 96 rows x 24 float4 = 2304 float4 (9 per thread)
#pragma unroll
    for (int it = 0; it < 9; ++it) {
        int idx = tid + 256 * it;
        int row = idx / 24, c = idx % 24;
        *((float4*)&Ws[row * WS_STRIDE + c * 4]) = ((const float4*)(W + (size_t)row * DIM))[c];
    }
    __syncthreads();

    int g = tid & 15;   // col group: j = g*6 + jj
    int r = tid >> 4;   // node group: n = r*4 + i
    float acc[4][6];
#pragma unroll
    for (int i = 0; i < 4; ++i)
#pragma unroll
        for (int jj = 0; jj < 6; ++jj) acc[i][jj] = 0.f;

#pragma unroll 8
    for (int k4 = 0; k4 < 24; ++k4) {
        float4 xv[4], wv[6];
#pragma unroll
        for (int i = 0; i < 4; ++i)
            xv[i] = *(const float4*)&Xs[(r * 4 + i) * XS_STRIDE + k4 * 4];
#pragma unroll
        for (int jj = 0; jj < 6; ++jj)
            wv[jj] = *(const float4*)&Ws[(g * 6 + jj) * WS_STRIDE + k4 * 4];
#pragma unroll
        for (int i = 0; i < 4; ++i)
#pragma unroll
            for (int jj = 0; jj < 6; ++jj)
                acc[i][jj] += xv[i].x * wv[jj].x + xv[i].y * wv[jj].y +
                              xv[i].z * wv[jj].z + xv[i].w * wv[jj].w;
    }

#pragma unroll
    for (int i = 0; i < 4; ++i) {
        int n = nbase + r * 4 + i;
        if (n < N_NODES) {
            float nm = norm[n];
#pragma unroll
            for (int jj = 0; jj < 6; ++jj) {
                int j = g * 6 + jj;
                out[(size_t)n * DIM + j] = (acc[i][jj] + b[j]) * nm;
            }
        }
    }
}

// ---------------- gather aggregation ----------------

template <bool DO_TANH>
__global__ void gather_agg(const float* __restrict__ feat, const int* __restrict__ offs,
                           const int2* __restrict__ entries, float* __restrict__ out) {
    int idx = blockIdx.x * blockDim.x + threadIdx.x;
    if (idx >= N_NODES * CHUNKS) return;
    int n = idx / CHUNKS;
    int c = idx - n * CHUNKS;
    int beg = offs[n], end = offs[n + 1];
    float4 acc = make_float4(0.f, 0.f, 0.f, 0.f);
    for (int p = beg; p < end; ++p) {
        int2 en = entries[p];
        float f = __int_as_float(en.y);
        float4 v = ((const float4*)(feat + (size_t)en.x * DIM))[c];
        acc.x += v.x * f; acc.y += v.y * f; acc.z += v.z * f; acc.w += v.w * f;
    }
    if (DO_TANH) {
        acc.x = tanhf(acc.x); acc.y = tanhf(acc.y);
        acc.z = tanhf(acc.z); acc.w = tanhf(acc.w);
    }
    ((float4*)out)[idx] = acc;
}

// ---------------- pooling ----------------

// 416 blocks * 192 threads = 79872 threads, multiple of 96 -> column loop-invariant
__global__ void tanh_colsum(const float* __restrict__ agg, float* __restrict__ pooled) {
    int gtid = blockIdx.x * blockDim.x + threadIdx.x;
    const int T = 416 * 192;
    float s = 0.f;
    for (int i = gtid; i < N_NODES * DIM; i += T) s += tanhf(agg[i]);
    atomicAdd(&pooled[gtid % DIM], s);
}

__global__ void final_tanh(const float* __restrict__ pooled, float* __restrict__ out) {
    int j = threadIdx.x;
    if (j < DIM) out[j] = tanhf(pooled[j] * (1.0f / N_NODES));
}

// ---------------- launch ----------------

extern "C" void kernel_launch(void* const* d_in, const int* in_sizes, int n_in,
                              void* d_out, int out_size, void* d_ws, size_t ws_size,
                              hipStream_t stream) {
    const float* inputs = (const float*)d_in[0];
    const float* W1     = (const float*)d_in[1];
    const float* b1     = (const float*)d_in[2];
    const float* W2     = (const float*)d_in[3];
    const float* b2     = (const float*)d_in[4];
    const float* factor = (const float*)d_in[5];
    const int*   src    = (const int*)d_in[6];
    const int*   dst    = (const int*)d_in[7];
    float* out = (float*)d_out;

    char* ws = (char*)d_ws;
    int*   deg     = (int*)(ws + 0);                 // 200 KB
    int*   offs    = (int*)(ws + 204800);            // 200 KB (+1)
    int*   cursor  = (int*)(ws + 409600);            // 200 KB
    float* norm    = (float*)(ws + 614400);          // 200 KB
    int2*  entries = (int2*)(ws + 819200);           // 6.4 MB
    float* bufA    = (float*)(ws + 7340032);         // 19.2 MB
    float* bufB    = (float*)(ws + 26542080);        // 19.2 MB
    float* pooled  = (float*)(ws + 45744128);        // 384 B

    // degree + CSR build + norm
    hipMemsetAsync(deg, 0, N_NODES * sizeof(int), stream);
    count_deg<<<(N_EDGES + 255) / 256, 256, 0, stream>>>(dst, deg);
    scan_deg_norm<<<1, 1024, 0, stream>>>(deg, offs, cursor, norm);
    fill_csr<<<(N_EDGES + 255) / 256, 256, 0, stream>>>(src, dst, factor, cursor, entries);

    const int GEMM_BLOCKS = (N_NODES + MT - 1) / MT;
    const int AGG_THREADS = N_NODES * CHUNKS;

    // layer 1
    gemm_tiled<<<GEMM_BLOCKS, 256, 0, stream>>>(inputs, W1, b1, norm, bufA);
    gather_agg<true><<<(AGG_THREADS + 255) / 256, 256, 0, stream>>>(bufA, offs, entries, bufB);

    // layer 2
    gemm_tiled<<<GEMM_BLOCKS, 256, 0, stream>>>(bufB, W2, b2, norm, bufA);
    gather_agg<false><<<(AGG_THREADS + 255) / 256, 256, 0, stream>>>(bufA, offs, entries, bufB);

    // pooled mean + tanh
    hipMemsetAsync(pooled, 0, DIM * sizeof(float), stream);
    tanh_colsum<<<416, 192, 0, stream>>>(bufB, pooled);
    final_tanh<<<1, 128, 0, stream>>>(pooled, out);
}

// Round 4
// 361.579 us; speedup vs baseline: 7.4824x; 1.4053x over previous
//
#include <hip/hip_runtime.h>
#include <math.h>

#define N_NODES 50000
#define N_EDGES 800000
#define DIM 96
#define CHUNKS (DIM / 4)          // 24 float4 chunks per node
#define SCAN_BLK 256
#define NBLK ((N_NODES + SCAN_BLK - 1) / SCAN_BLK)   // 196

// ---------------- degree / CSR build ----------------

__global__ void count_deg(const int* __restrict__ dst, int* __restrict__ deg) {
    int i = blockIdx.x * blockDim.x + threadIdx.x;
    if (i < N_EDGES) atomicAdd(&deg[dst[i]], 1);
}

// per-block chunk sums (coalesced)
__global__ void block_partials(const int* __restrict__ deg, int* __restrict__ partials) {
    int b = blockIdx.x, t = threadIdx.x;
    int idx = b * SCAN_BLK + t;
    int v = (idx < N_NODES) ? deg[idx] : 0;
#pragma unroll
    for (int off = 32; off > 0; off >>= 1) v += __shfl_down(v, off, 64);
    __shared__ int ws[4];
    if ((t & 63) == 0) ws[t >> 6] = v;
    __syncthreads();
    if (t == 0) partials[b] = ws[0] + ws[1] + ws[2] + ws[3];
}

// scan the 196 partials in one small block -> exclusive prefixes
__global__ void scan_partials(const int* __restrict__ partials, int* __restrict__ pprefix) {
    __shared__ int sm[SCAN_BLK];
    int t = threadIdx.x;
    int v = (t < NBLK) ? partials[t] : 0;
    sm[t] = v;
    __syncthreads();
    for (int off = 1; off < SCAN_BLK; off <<= 1) {
        int u = (t >= off) ? sm[t - off] : 0;
        __syncthreads();
        sm[t] += u;
        __syncthreads();
    }
    if (t < NBLK) pprefix[t] = sm[t] - v;
}

// per-chunk exclusive scan + block prefix -> offs/cursor; fused norm
__global__ void expand_scan(const int* __restrict__ deg, const int* __restrict__ pprefix,
                            int* __restrict__ offs, int* __restrict__ cursor,
                            float* __restrict__ norm) {
    __shared__ int sm[SCAN_BLK];
    int b = blockIdx.x, t = threadIdx.x;
    int idx = b * SCAN_BLK + t;
    int v = (idx < N_NODES) ? deg[idx] : 0;
    sm[t] = v;
    __syncthreads();
    for (int off = 1; off < SCAN_BLK; off <<= 1) {
        int u = (t >= off) ? sm[t - off] : 0;
        __syncthreads();
        sm[t] += u;
        __syncthreads();
    }
    if (idx < N_NODES) {
        int e = pprefix[b] + sm[t] - v;   // global exclusive prefix
        offs[idx] = e;
        cursor[idx] = e;
        norm[idx] = rsqrtf(fmaxf((float)v, 1.0f));
    }
    if (b == 0 && t == 0) offs[N_NODES] = N_EDGES;  // sum(deg) == N_EDGES statically
}

__global__ void fill_csr(const int* __restrict__ src, const int* __restrict__ dst,
                         const float* __restrict__ factor,
                         int* __restrict__ cursor, int2* __restrict__ entries) {
    int e = blockIdx.x * blockDim.x + threadIdx.x;
    if (e >= N_EDGES) return;
    int pos = atomicAdd(&cursor[dst[e]], 1);
    entries[pos] = make_int2(src[e], __float_as_int(factor[e]));
}

// ---------------- LDS-tiled GEMM:  out[n][j] = (dot(X[n,:],W[j,:]) + b[j]) * norm[n] ----------------

#define MT 64            // nodes per block
#define XS_STRIDE 100
#define WS_STRIDE 100

__global__ void gemm_tiled(const float* __restrict__ X, const float* __restrict__ W,
                           const float* __restrict__ b, const float* __restrict__ norm,
                           float* __restrict__ out) {
    __shared__ float Xs[MT * XS_STRIDE];    // 25.6 KB
    __shared__ float Ws[DIM * WS_STRIDE];   // 38.4 KB
    int tid = threadIdx.x;
    int nbase = blockIdx.x * MT;

#pragma unroll
    for (int it = 0; it < 6; ++it) {
        int idx = tid + 256 * it;
        int row = idx / 24, c = idx % 24;
        int n = nbase + row;
        float4 v = make_float4(0.f, 0.f, 0.f, 0.f);
        if (n < N_NODES) v = ((const float4*)(X + (size_t)n * DIM))[c];
        *((float4*)&Xs[row * XS_STRIDE + c * 4]) = v;
    }
#pragma unroll
    for (int it = 0; it < 9; ++it) {
        int idx = tid + 256 * it;
        int row = idx / 24, c = idx % 24;
        *((float4*)&Ws[row * WS_STRIDE + c * 4]) = ((const float4*)(W + (size_t)row * DIM))[c];
    }
    __syncthreads();

    int g = tid & 15;   // col group: j = g*6 + jj
    int r = tid >> 4;   // node group: n = r*4 + i
    float acc[4][6];
#pragma unroll
    for (int i = 0; i < 4; ++i)
#pragma unroll
        for (int jj = 0; jj < 6; ++jj) acc[i][jj] = 0.f;

#pragma unroll 8
    for (int k4 = 0; k4 < 24; ++k4) {
        float4 xv[4], wv[6];
#pragma unroll
        for (int i = 0; i < 4; ++i)
            xv[i] = *(const float4*)&Xs[(r * 4 + i) * XS_STRIDE + k4 * 4];
#pragma unroll
        for (int jj = 0; jj < 6; ++jj)
            wv[jj] = *(const float4*)&Ws[(g * 6 + jj) * WS_STRIDE + k4 * 4];
#pragma unroll
        for (int i = 0; i < 4; ++i)
#pragma unroll
            for (int jj = 0; jj < 6; ++jj)
                acc[i][jj] += xv[i].x * wv[jj].x + xv[i].y * wv[jj].y +
                              xv[i].z * wv[jj].z + xv[i].w * wv[jj].w;
    }

#pragma unroll
    for (int i = 0; i < 4; ++i) {
        int n = nbase + r * 4 + i;
        if (n < N_NODES) {
            float nm = norm[n];
#pragma unroll
            for (int jj = 0; jj < 6; ++jj) {
                int j = g * 6 + jj;
                out[(size_t)n * DIM + j] = (acc[i][jj] + b[j]) * nm;
            }
        }
    }
}

// ---------------- gather aggregation (software-pipelined entry prefetch) ----------------

template <bool DO_TANH>
__global__ void gather_agg(const float* __restrict__ feat, const int* __restrict__ offs,
                           const int2* __restrict__ entries, float* __restrict__ out) {
    int idx = blockIdx.x * blockDim.x + threadIdx.x;
    if (idx >= N_NODES * CHUNKS) return;
    int n = idx / CHUNKS;
    int c = idx - n * CHUNKS;
    int beg = offs[n], end = offs[n + 1];
    float4 acc = make_float4(0.f, 0.f, 0.f, 0.f);
    if (beg < end) {
        int2 en = entries[beg];
        for (int p = beg; p < end; ++p) {
            int2 cur = en;
            if (p + 1 < end) en = entries[p + 1];   // prefetch overlaps feat load
            float f = __int_as_float(cur.y);
            float4 v = ((const float4*)(feat + (size_t)cur.x * DIM))[c];
            acc.x += v.x * f; acc.y += v.y * f; acc.z += v.z * f; acc.w += v.w * f;
        }
    }
    if (DO_TANH) {
        acc.x = tanhf(acc.x); acc.y = tanhf(acc.y);
        acc.z = tanhf(acc.z); acc.w = tanhf(acc.w);
    }
    ((float4*)out)[idx] = acc;
}

// ---------------- pooling ----------------

__global__ void tanh_colsum(const float* __restrict__ agg, float* __restrict__ pooled) {
    int gtid = blockIdx.x * blockDim.x + threadIdx.x;
    const int T = 416 * 192;
    float s = 0.f;
    for (int i = gtid; i < N_NODES * DIM; i += T) s += tanhf(agg[i]);
    atomicAdd(&pooled[gtid % DIM], s);
}

__global__ void final_tanh(const float* __restrict__ pooled, float* __restrict__ out) {
    int j = threadIdx.x;
    if (j < DIM) out[j] = tanhf(pooled[j] * (1.0f / N_NODES));
}

// ---------------- launch ----------------

extern "C" void kernel_launch(void* const* d_in, const int* in_sizes, int n_in,
                              void* d_out, int out_size, void* d_ws, size_t ws_size,
                              hipStream_t stream) {
    const float* inputs = (const float*)d_in[0];
    const float* W1     = (const float*)d_in[1];
    const float* b1     = (const float*)d_in[2];
    const float* W2     = (const float*)d_in[3];
    const float* b2     = (const float*)d_in[4];
    const float* factor = (const float*)d_in[5];
    const int*   src    = (const int*)d_in[6];
    const int*   dst    = (const int*)d_in[7];
    float* out = (float*)d_out;

    char* ws = (char*)d_ws;
    int*   deg      = (int*)(ws + 0);                 // 200 KB
    int*   offs     = (int*)(ws + 204800);            // 200 KB (+1)
    int*   cursor   = (int*)(ws + 409600);            // 200 KB
    float* norm     = (float*)(ws + 614400);          // 200 KB
    int*   partials = (int*)(ws + 819200);            // 1 KB
    int*   pprefix  = (int*)(ws + 821248);            // 1 KB
    int2*  entries  = (int2*)(ws + 823296);           // 6.4 MB
    float* bufA     = (float*)(ws + 7340032);         // 19.2 MB
    float* bufB     = (float*)(ws + 26542080);        // 19.2 MB
    float* pooled   = (float*)(ws + 45744128);        // 384 B

    // degree + CSR build + norm
    hipMemsetAsync(deg, 0, N_NODES * sizeof(int), stream);
    count_deg<<<(N_EDGES + 255) / 256, 256, 0, stream>>>(dst, deg);
    block_partials<<<NBLK, SCAN_BLK, 0, stream>>>(deg, partials);
    scan_partials<<<1, SCAN_BLK, 0, stream>>>(partials, pprefix);
    expand_scan<<<NBLK, SCAN_BLK, 0, stream>>>(deg, pprefix, offs, cursor, norm);
    fill_csr<<<(N_EDGES + 255) / 256, 256, 0, stream>>>(src, dst, factor, cursor, entries);

    const int GEMM_BLOCKS = (N_NODES + MT - 1) / MT;
    const int AGG_THREADS = N_NODES * CHUNKS;

    // layer 1
    gemm_tiled<<<GEMM_BLOCKS, 256, 0, stream>>>(inputs, W1, b1, norm, bufA);
    gather_agg<true><<<(AGG_THREADS + 255) / 256, 256, 0, stream>>>(bufA, offs, entries, bufB);

    // layer 2
    gemm_tiled<<<GEMM_BLOCKS, 256, 0, stream>>>(bufB, W2, b2, norm, bufA);
    gather_agg<false><<<(AGG_THREADS + 255) / 256, 256, 0, stream>>>(bufA, offs, entries, bufB);

    // pooled mean + tanh
    hipMemsetAsync(pooled, 0, DIM * sizeof(float), stream);
    tanh_colsum<<<416, 192, 0, stream>>>(bufB, pooled);
    final_tanh<<<1, 128, 0, stream>>>(pooled, out);
}

// Round 5
// 346.348 us; speedup vs baseline: 7.8114x; 1.0440x over previous
//
#include <hip/hip_runtime.h>
#include <math.h>

#define N_NODES 50000
#define N_EDGES 800000
#define DIM 96
#define CHUNKS (DIM / 4)          // 24 float4 chunks per node
#define SCAN_BLK 256
#define NBLK ((N_NODES + SCAN_BLK - 1) / SCAN_BLK)   // 196

__device__ __forceinline__ float fast_tanh(float x) {
    float ax = fabsf(x);
    float t = __expf(-2.0f * ax);        // v_exp_f32-based, ~2 ulp
    float r = (1.0f - t) / (1.0f + t);
    return copysignf(r, x);
}

// ---------------- linked-list CSR build ----------------

// head[dst] -> newest edge; next[e] -> previous edge with same dst (coalesced write)
__global__ void link_edges(const int* __restrict__ dst, int* __restrict__ head,
                           int* __restrict__ nxt) {
    int e = blockIdx.x * blockDim.x + threadIdx.x;
    if (e >= N_EDGES) return;
    int old = atomicExch(&head[dst[e]], e);
    nxt[e] = old;
}

// walk list: deg + norm per node; fused per-block partial sum of deg
__global__ void walk_count_partials(const int* __restrict__ head, const int* __restrict__ nxt,
                                    int* __restrict__ deg, float* __restrict__ norm,
                                    int* __restrict__ partials) {
    int b = blockIdx.x, t = threadIdx.x;
    int n = b * SCAN_BLK + t;
    int cnt = 0;
    if (n < N_NODES) {
        int p = head[n];
        while (p >= 0) { ++cnt; p = nxt[p]; }
        deg[n] = cnt;
        norm[n] = rsqrtf(fmaxf((float)cnt, 1.0f));
    }
    int v = cnt;
#pragma unroll
    for (int off = 32; off > 0; off >>= 1) v += __shfl_down(v, off, 64);
    __shared__ int ws[4];
    if ((t & 63) == 0) ws[t >> 6] = v;
    __syncthreads();
    if (t == 0) partials[b] = ws[0] + ws[1] + ws[2] + ws[3];
}

__global__ void scan_partials(const int* __restrict__ partials, int* __restrict__ pprefix) {
    __shared__ int sm[SCAN_BLK];
    int t = threadIdx.x;
    int v = (t < NBLK) ? partials[t] : 0;
    sm[t] = v;
    __syncthreads();
    for (int off = 1; off < SCAN_BLK; off <<= 1) {
        int u = (t >= off) ? sm[t - off] : 0;
        __syncthreads();
        sm[t] += u;
        __syncthreads();
    }
    if (t < NBLK) pprefix[t] = sm[t] - v;
}

// LDS scan -> offs; walk list writing entries sequentially into own segment
__global__ void scan_compact(const int* __restrict__ deg, const int* __restrict__ pprefix,
                             const int* __restrict__ head, const int* __restrict__ nxt,
                             const int* __restrict__ src, const float* __restrict__ factor,
                             int* __restrict__ offs, int2* __restrict__ entries) {
    __shared__ int sm[SCAN_BLK];
    int b = blockIdx.x, t = threadIdx.x;
    int idx = b * SCAN_BLK + t;
    int v = (idx < N_NODES) ? deg[idx] : 0;
    sm[t] = v;
    __syncthreads();
    for (int off = 1; off < SCAN_BLK; off <<= 1) {
        int u = (t >= off) ? sm[t - off] : 0;
        __syncthreads();
        sm[t] += u;
        __syncthreads();
    }
    if (idx < N_NODES) {
        int o = pprefix[b] + sm[t] - v;   // global exclusive prefix
        offs[idx] = o;
        int p = head[idx];
        while (p >= 0) {
            entries[o++] = make_int2(src[p], __float_as_int(factor[p]));
            p = nxt[p];
        }
    }
    if (b == 0 && t == 0) offs[N_NODES] = N_EDGES;
}

// ---------------- LDS-tiled GEMM:  out[n][j] = (dot(X[n,:],W[j,:]) + b[j]) * norm[n] ----------------

#define MT 64            // nodes per block
#define XS_STRIDE 100    // 4 distinct addrs/wave, 2-way bank overlap (free)
#define WS_STRIDE 97     // 16 addrs/wave span 64 bank-slots -> exactly 2-way (free)

__global__ void gemm_tiled(const float* __restrict__ X, const float* __restrict__ W,
                           const float* __restrict__ b, const float* __restrict__ norm,
                           float* __restrict__ out) {
    __shared__ float Xs[MT * XS_STRIDE];    // 25.6 KB
    __shared__ float Ws[DIM * WS_STRIDE];   // 37.25 KB
    int tid = threadIdx.x;
    int nbase = blockIdx.x * MT;

#pragma unroll
    for (int it = 0; it < 6; ++it) {
        int idx = tid + 256 * it;
        int row = idx / 24, c = idx % 24;
        int n = nbase + row;
        float4 v = make_float4(0.f, 0.f, 0.f, 0.f);
        if (n < N_NODES) v = ((const float4*)(X + (size_t)n * DIM))[c];
        *((float4*)&Xs[row * XS_STRIDE + c * 4]) = v;
    }
#pragma unroll
    for (int it = 0; it < 9; ++it) {
        int idx = tid + 256 * it;
        int row = idx / 24, c = idx % 24;
        *((float4*)&Ws[row * WS_STRIDE + c * 4]) = ((const float4*)(W + (size_t)row * DIM))[c];
    }
    __syncthreads();

    int g = tid & 15;   // col group: j = g*6 + jj
    int r = tid >> 4;   // node group: n = r*4 + i
    float acc[4][6];
#pragma unroll
    for (int i = 0; i < 4; ++i)
#pragma unroll
        for (int jj = 0; jj < 6; ++jj) acc[i][jj] = 0.f;

#pragma unroll 8
    for (int k4 = 0; k4 < 24; ++k4) {
        float4 xv[4], wv[6];
#pragma unroll
        for (int i = 0; i < 4; ++i)
            xv[i] = *(const float4*)&Xs[(r * 4 + i) * XS_STRIDE + k4 * 4];
#pragma unroll
        for (int jj = 0; jj < 6; ++jj)
            wv[jj] = *(const float4*)&Ws[(g * 6 + jj) * WS_STRIDE + k4 * 4];
#pragma unroll
        for (int i = 0; i < 4; ++i)
#pragma unroll
            for (int jj = 0; jj < 6; ++jj)
                acc[i][jj] += xv[i].x * wv[jj].x + xv[i].y * wv[jj].y +
                              xv[i].z * wv[jj].z + xv[i].w * wv[jj].w;
    }

#pragma unroll
    for (int i = 0; i < 4; ++i) {
        int n = nbase + r * 4 + i;
        if (n < N_NODES) {
            float nm = norm[n];
#pragma unroll
            for (int jj = 0; jj < 6; ++jj) {
                int j = g * 6 + jj;
                out[(size_t)n * DIM + j] = (acc[i][jj] + b[j]) * nm;
            }
        }
    }
}

// ---------------- gather aggregation (unroll x2, dual accumulators) ----------------

template <bool DO_TANH>
__global__ void gather_agg(const float* __restrict__ feat, const int* __restrict__ offs,
                           const int2* __restrict__ entries, float* __restrict__ out) {
    int idx = blockIdx.x * blockDim.x + threadIdx.x;
    if (idx >= N_NODES * CHUNKS) return;
    int n = idx / CHUNKS;
    int c = idx - n * CHUNKS;
    int beg = offs[n], end = offs[n + 1];
    float4 acc0 = make_float4(0.f, 0.f, 0.f, 0.f);
    float4 acc1 = make_float4(0.f, 0.f, 0.f, 0.f);
    int p = beg;
    for (; p + 1 < end; p += 2) {
        int2 e0 = entries[p];
        int2 e1 = entries[p + 1];
        float f0 = __int_as_float(e0.y);
        float f1 = __int_as_float(e1.y);
        float4 v0 = ((const float4*)(feat + (size_t)e0.x * DIM))[c];
        float4 v1 = ((const float4*)(feat + (size_t)e1.x * DIM))[c];
        acc0.x += v0.x * f0; acc0.y += v0.y * f0; acc0.z += v0.z * f0; acc0.w += v0.w * f0;
        acc1.x += v1.x * f1; acc1.y += v1.y * f1; acc1.z += v1.z * f1; acc1.w += v1.w * f1;
    }
    if (p < end) {
        int2 e0 = entries[p];
        float f0 = __int_as_float(e0.y);
        float4 v0 = ((const float4*)(feat + (size_t)e0.x * DIM))[c];
        acc0.x += v0.x * f0; acc0.y += v0.y * f0; acc0.z += v0.z * f0; acc0.w += v0.w * f0;
    }
    acc0.x += acc1.x; acc0.y += acc1.y; acc0.z += acc1.z; acc0.w += acc1.w;
    if (DO_TANH) {
        acc0.x = fast_tanh(acc0.x); acc0.y = fast_tanh(acc0.y);
        acc0.z = fast_tanh(acc0.z); acc0.w = fast_tanh(acc0.w);
    }
    ((float4*)out)[idx] = acc0;
}

// ---------------- pooling ----------------

__global__ void tanh_colsum(const float* __restrict__ agg, float* __restrict__ pooled) {
    int gtid = blockIdx.x * blockDim.x + threadIdx.x;
    const int T = 416 * 192;   // multiple of 96 -> column loop-invariant
    float s = 0.f;
    for (int i = gtid; i < N_NODES * DIM; i += T) s += fast_tanh(agg[i]);
    atomicAdd(&pooled[gtid % DIM], s);
}

__global__ void final_tanh(const float* __restrict__ pooled, float* __restrict__ out) {
    int j = threadIdx.x;
    if (j < DIM) out[j] = tanhf(pooled[j] * (1.0f / N_NODES));
}

// ---------------- launch ----------------

extern "C" void kernel_launch(void* const* d_in, const int* in_sizes, int n_in,
                              void* d_out, int out_size, void* d_ws, size_t ws_size,
                              hipStream_t stream) {
    const float* inputs = (const float*)d_in[0];
    const float* W1     = (const float*)d_in[1];
    const float* b1     = (const float*)d_in[2];
    const float* W2     = (const float*)d_in[3];
    const float* b2     = (const float*)d_in[4];
    const float* factor = (const float*)d_in[5];
    const int*   src    = (const int*)d_in[6];
    const int*   dst    = (const int*)d_in[7];
    float* out = (float*)d_out;

    char* ws = (char*)d_ws;
    int*   head     = (int*)(ws + 0);                 // 200 KB  (pad to 256K)
    int*   nxt      = (int*)(ws + 262144);            // 3.2 MB  (to 3670016)
    int*   deg      = (int*)(ws + 3670016);           // 200 KB
    int*   offs     = (int*)(ws + 3932160);           // 200 KB (+1)
    float* norm     = (float*)(ws + 4194304);         // 200 KB
    int*   partials = (int*)(ws + 4456448);           // 1 KB
    int*   pprefix  = (int*)(ws + 4458496);           // 1 KB
    int2*  entries  = (int2*)(ws + 4718592);          // 6.4 MB
    float* bufA     = (float*)(ws + 11534336);        // 19.2 MB
    float* bufB     = (float*)(ws + 30734336);        // 19.2 MB
    float* pooled   = (float*)(ws + 49934336);        // 384 B

    // linked-list CSR build
    hipMemsetAsync(head, 0xFF, N_NODES * sizeof(int), stream);   // head = -1
    link_edges<<<(N_EDGES + 255) / 256, 256, 0, stream>>>(dst, head, nxt);
    walk_count_partials<<<NBLK, SCAN_BLK, 0, stream>>>(head, nxt, deg, norm, partials);
    scan_partials<<<1, SCAN_BLK, 0, stream>>>(partials, pprefix);
    scan_compact<<<NBLK, SCAN_BLK, 0, stream>>>(deg, pprefix, head, nxt, src, factor,
                                                offs, entries);

    const int GEMM_BLOCKS = (N_NODES + MT - 1) / MT;
    const int AGG_THREADS = N_NODES * CHUNKS;

    // layer 1
    gemm_tiled<<<GEMM_BLOCKS, 256, 0, stream>>>(inputs, W1, b1, norm, bufA);
    gather_agg<true><<<(AGG_THREADS + 255) / 256, 256, 0, stream>>>(bufA, offs, entries, bufB);

    // layer 2
    gemm_tiled<<<GEMM_BLOCKS, 256, 0, stream>>>(bufB, W2, b2, norm, bufA);
    gather_agg<false><<<(AGG_THREADS + 255) / 256, 256, 0, stream>>>(bufA, offs, entries, bufB);

    // pooled mean + tanh
    hipMemsetAsync(pooled, 0, DIM * sizeof(float), stream);
    tanh_colsum<<<416, 192, 0, stream>>>(bufB, pooled);
    final_tanh<<<1, 128, 0, stream>>>(pooled, out);
}